// Round 5
// baseline (197.387 us; speedup 1.0000x reference)
//
#include <hip/hip_runtime.h>

#define U_CNT 16384
#define I_CNT 8192
#define DIM 64
#define BAND 16                   // output rows per gemm block
#define CHUNK 256                 // output cols per chunk iteration
#define NCHUNK (I_CNT / CHUNK)    // 32
#define LDS_STRIDE 260            // floats; bank = (16g + r) % 32 -> 2-way (free)
#define NEG_LOG2E (-1.4426950408889634f)

typedef __bf16 bf16x8 __attribute__((ext_vector_type(8)));
typedef float f32x4 __attribute__((ext_vector_type(4)));

__device__ __forceinline__ unsigned short f32_to_bf16_rtn(float f) {
    unsigned int b = __float_as_uint(f);
    b += 0x7fffu + ((b >> 16) & 1u);
    return (unsigned short)(b >> 16);
}

// Fused prep + pfull:
//   blocks [0, 2048):    Q1 -> bf16 (covers I_CNT*DIM = 524288 elems).
//   blocks [2048, 6144): one wave per user; binary-search segment bounds in
//                        sorted seg_ids, sum Q2 rows (lane = dim), scale by
//                        rsqrt(count), add P, write bf16 A-matrix.
__global__ __launch_bounds__(256) void prep_pfull_kernel(
    const float* __restrict__ Q1, unsigned short* __restrict__ Q1bf,
    const float* __restrict__ Q2, const float* __restrict__ P,
    const int* __restrict__ items, const int* __restrict__ segs,
    int nnz, unsigned short* __restrict__ Pbf)
{
    if (blockIdx.x < 2048) {
        int i = blockIdx.x * 256 + threadIdx.x;
        Q1bf[i] = f32_to_bf16_rtn(Q1[i]);
        return;
    }
    int u = ((blockIdx.x - 2048) * 256 + threadIdx.x) >> 6;
    int lane = threadIdx.x & 63;
    if (u >= U_CNT) return;

    int lo = 0, hi = nnz;
    while (lo < hi) { int m = (lo + hi) >> 1; if (segs[m] < u) lo = m + 1; else hi = m; }
    int start = lo;
    hi = nnz;
    while (lo < hi) { int m = (lo + hi) >> 1; if (segs[m] <= u) lo = m + 1; else hi = m; }
    int end = lo;

    float s = 0.f;
    int j = start;
    for (; j + 3 < end; j += 4) {
        int i0 = items[j], i1 = items[j + 1], i2 = items[j + 2], i3 = items[j + 3];
        float v0 = Q2[i0 * DIM + lane];
        float v1 = Q2[i1 * DIM + lane];
        float v2 = Q2[i2 * DIM + lane];
        float v3 = Q2[i3 * DIM + lane];
        s += (v0 + v1) + (v2 + v3);
    }
    for (; j < end; ++j) s += Q2[items[j] * DIM + lane];

    int cnt = end - start;              // guaranteed >= 1
    float val = s * rsqrtf((float)cnt) + P[u * DIM + lane];
    Pbf[u * DIM + lane] = f32_to_bf16_rtn(val);
}

// Band-sweep GEMM + sigmoid. Block = 16-row band x 8192 cols, 32 chunks of
// 256 cols, phase-staggered per block. Epilogue: sigmoid in acc layout ->
// BLOCK-wide LDS tile [16][256] (double-buffered, 1 barrier/chunk) ->
// store phase where wave wid owns rows wid*4..wid*4+3 and EVERY STORE
// INSTRUCTION writes 1 KB fully contiguous of ONE row (64 lanes x 16B,
// matching the 6.7 TB/s fill kernel's burst shape). Rows advance in strictly
// ascending 1 KB bursts. Nontemporal is now safe (full-line bursts) and
// avoids cycling 536 MB through the 256 MB L3.
__global__ __launch_bounds__(256) void gemm_sig_kernel(
    const unsigned short* __restrict__ Abf, const unsigned short* __restrict__ Bbf,
    const float* __restrict__ bu, const float* __restrict__ bi,
    float* __restrict__ out)
{
    const int lane = threadIdx.x & 63;
    const int wid  = threadIdx.x >> 6;      // 0..3: 64-col sub-band within chunk
    const int r = lane & 15, g = lane >> 4;
    const int band = blockIdx.x * BAND;

    __shared__ float lds[2][BAND][LDS_STRIDE];

    // A fragments for the whole band (rows band..band+15), both K-steps.
    bf16x8 a[2];
#pragma unroll
    for (int ks = 0; ks < 2; ++ks)
        a[ks] = *reinterpret_cast<const bf16x8*>(&Abf[(band + r) * DIM + ks * 32 + g * 8]);

    // bu for the 4 acc rows this lane holds (tile row = g*4 + j), pre-biased.
    float bu_g[4];
#pragma unroll
    for (int j = 0; j < 4; ++j) bu_g[j] = bu[band + g * 4 + j] + 0.05f;

    const int c0 = (blockIdx.x * 7) & (NCHUNK - 1);

    for (int cc = 0; cc < NCHUNK; ++cc) {
        const int c = (cc + c0) & (NCHUNK - 1);
        const int colbase = c * CHUNK;
        const int col0 = colbase + wid * 64;
        const int p = cc & 1;

        bf16x8 b[4][2];
        float bi_f[4];
#pragma unroll
        for (int nf = 0; nf < 4; ++nf) {
            bi_f[nf] = bi[col0 + nf * 16 + r];
#pragma unroll
            for (int ks = 0; ks < 2; ++ks)
                b[nf][ks] = *reinterpret_cast<const bf16x8*>(
                    &Bbf[(col0 + nf * 16 + r) * DIM + ks * 32 + g * 8]);
        }

        f32x4 acc[4] = {};
#pragma unroll
        for (int ks = 0; ks < 2; ++ks)
#pragma unroll
            for (int nf = 0; nf < 4; ++nf)
                acc[nf] = __builtin_amdgcn_mfma_f32_16x16x32_bf16(
                    a[ks], b[nf][ks], acc[nf], 0, 0, 0);

        // Sigmoid in acc layout (row = g*4+j, col = wid*64 + nf*16 + r),
        // write transposed into the block-wide LDS tile.
#pragma unroll
        for (int nf = 0; nf < 4; ++nf)
#pragma unroll
            for (int j = 0; j < 4; ++j) {
                float x = (acc[nf][j] + bu_g[j] + bi_f[nf]) * NEG_LOG2E;
                float e = __builtin_amdgcn_exp2f(x);
                float v = 5.f * __builtin_amdgcn_rcpf(1.f + e);
                lds[p][g * 4 + j][wid * 64 + nf * 16 + r] = v;
            }

        __syncthreads();   // single barrier per chunk; double-buffer makes it safe

        // Store phase: wave wid owns rows wid*4..wid*4+3. Each instruction:
        // 64 lanes x f32x4 = 1 KB fully contiguous of one output row.
#pragma unroll
        for (int i = 0; i < 4; ++i) {
            const int row = wid * 4 + i;
            f32x4 v = *reinterpret_cast<const f32x4*>(&lds[p][row][lane * 4]);
            __builtin_nontemporal_store(v, reinterpret_cast<f32x4*>(
                &out[(size_t)(band + row) * I_CNT + colbase + lane * 4]));
        }
    }
}

extern "C" void kernel_launch(void* const* d_in, const int* in_sizes, int n_in,
                              void* d_out, int out_size, void* d_ws, size_t ws_size,
                              hipStream_t stream)
{
    const float* Q1 = (const float*)d_in[0];
    const float* Q2 = (const float*)d_in[1];
    const float* P  = (const float*)d_in[2];
    const float* bu = (const float*)d_in[3];
    const float* bi = (const float*)d_in[4];
    const int* items = (const int*)d_in[5];
    const int* segs  = (const int*)d_in[6];
    const int nnz = in_sizes[5];

    unsigned short* Pbf  = (unsigned short*)d_ws;            // 2 MB
    unsigned short* Q1bf = Pbf + U_CNT * DIM;                // 1 MB

    prep_pfull_kernel<<<2048 + U_CNT / 4, 256, 0, stream>>>(
        Q1, Q1bf, Q2, P, items, segs, nnz, Pbf);
    gemm_sig_kernel<<<U_CNT / BAND, 256, 0, stream>>>(Pbf, Q1bf, bu, bi, (float*)d_out);
}